// Round 1
// baseline (490.645 us; speedup 1.0000x reference)
//
#include <hip/hip_runtime.h>

typedef unsigned short u16;
typedef __bf16 bf16x8 __attribute__((ext_vector_type(8)));
typedef float f32x4 __attribute__((ext_vector_type(4)));

#define BB 4
#define TT 4096
#define HID 1024
#define NH 16
#define HD 64
#define BT (BB*TT)          // 16384 rows
#define NCH 32              // chunks over T
#define CLEN (TT/NCH)       // 128

__device__ __forceinline__ float bf2f(u16 u) {
    return __uint_as_float(((unsigned)u) << 16);
}
__device__ __forceinline__ u16 f2bf(float f) {
    unsigned u = __float_as_uint(f);
    unsigned r = 0x7FFFu + ((u >> 16) & 1u);
    return (u16)((u + r) >> 16);
}
__device__ __forceinline__ float phi(float x) {      // elu(x)+1
    return x > 0.f ? x + 1.f : __expf(x);
}
__device__ __forceinline__ float sigmoidf(float x) {
    return 1.f / (1.f + __expf(-x));
}

// ---------------- fp32 -> bf16 convert (vectorized x4) ----------------
__global__ void f32_to_bf16_v4(const float4* __restrict__ in, u16* __restrict__ out, int n4) {
    int i = blockIdx.x * 256 + threadIdx.x;
    if (i >= n4) return;
    float4 f = in[i];
    ushort4 u;
    u.x = f2bf(f.x); u.y = f2bf(f.y); u.z = f2bf(f.z); u.w = f2bf(f.w);
    ((ushort4*)out)[i] = u;
}

// ---------------- MFMA GEMM: C[M,N] = A[M,K] @ W[N,K]^T (both K-major bf16) ---------
// 128x128 tile, BK=64, 4 waves (each 64x64 via 4x4 of 16x16x32 mfma),
// global_load_lds width-16 staging (m97 structure).
// EPI 0: store bf16 (qkv).  EPI 1: gate epilogue.  EPI 2: store fp32 (final).
template<int EPI>
__global__ __launch_bounds__(256)
void gemm_bt(const u16* __restrict__ A, const u16* __restrict__ Bm,
             int M, int N, int K, void* __restrict__ Cout,
             const float* __restrict__ bg,          // EPI1: bias
             const u16* __restrict__ attn,          // EPI1: attn (bf16, [BT,HID])
             const u16* __restrict__ qkv)           // EPI1: qkv (bf16, [BT,3*HID]) for v
{
    __shared__ u16 As[128 * 64];
    __shared__ u16 Bs[128 * 64];
    const int tid  = threadIdx.x;
    const int wave = tid >> 6;
    const int lane = tid & 63;
    const int m0 = blockIdx.y * 128;
    const int n0 = blockIdx.x * 128;
    const int mw = (wave & 1) * 64;
    const int nw = (wave >> 1) * 64;
    const int r16 = lane & 15;
    const int q8  = (lane >> 4) * 8;

    f32x4 acc[4][4];
    #pragma unroll
    for (int i = 0; i < 4; ++i)
        #pragma unroll
        for (int j = 0; j < 4; ++j)
            acc[i][j] = (f32x4){0.f, 0.f, 0.f, 0.f};

    for (int k0 = 0; k0 < K; k0 += 64) {
        #pragma unroll
        for (int i = 0; i < 4; ++i) {
            int s   = i * 4 + wave;          // segment 0..15 (wave-uniform)
            int idx = s * 64 + lane;         // 0..1023
            int row = idx >> 3;
            int ch  = idx & 7;
            const u16* gA = A  + (size_t)(m0 + row) * K + k0 + ch * 8;
            const u16* gB = Bm + (size_t)(n0 + row) * K + k0 + ch * 8;
            __builtin_amdgcn_global_load_lds(
                (const __attribute__((address_space(1))) void*)gA,
                (__attribute__((address_space(3))) void*)&As[s * 512], 16, 0, 0);
            __builtin_amdgcn_global_load_lds(
                (const __attribute__((address_space(1))) void*)gB,
                (__attribute__((address_space(3))) void*)&Bs[s * 512], 16, 0, 0);
        }
        __syncthreads();   // drains vmcnt(0) -> LDS writes visible
        #pragma unroll
        for (int s2 = 0; s2 < 2; ++s2) {
            bf16x8 af[4], bq[4];
            #pragma unroll
            for (int i = 0; i < 4; ++i)
                af[i] = *(const bf16x8*)&As[(mw + i * 16 + r16) * 64 + s2 * 32 + q8];
            #pragma unroll
            for (int j = 0; j < 4; ++j)
                bq[j] = *(const bf16x8*)&Bs[(nw + j * 16 + r16) * 64 + s2 * 32 + q8];
            #pragma unroll
            for (int i = 0; i < 4; ++i)
                #pragma unroll
                for (int j = 0; j < 4; ++j)
                    acc[i][j] = __builtin_amdgcn_mfma_f32_16x16x32_bf16(af[i], bq[j], acc[i][j], 0, 0, 0);
        }
        __syncthreads();   // all reads done before next stage overwrites
    }

    // epilogue: C/D layout col=lane&15, row=(lane>>4)*4+reg  [m89/m91 verified]
    #pragma unroll
    for (int i = 0; i < 4; ++i) {
        int rowb = m0 + mw + i * 16 + (lane >> 4) * 4;
        #pragma unroll
        for (int j = 0; j < 4; ++j) {
            int col = n0 + nw + j * 16 + r16;
            #pragma unroll
            for (int r = 0; r < 4; ++r) {
                float v = acc[i][j][r];
                size_t row = (size_t)(rowb + r);
                if (EPI == 0) {
                    ((u16*)Cout)[row * N + col] = f2bf(v);
                } else if (EPI == 1) {
                    float g  = sigmoidf(v + bg[col]);
                    float at = bf2f(attn[row * HID + col]);
                    float vd = bf2f(qkv[row * (3 * HID) + 2 * HID + col]);
                    ((u16*)Cout)[row * HID + col] = f2bf(g * at + (1.f - g) * vd);
                } else {
                    ((float*)Cout)[row * N + col] = v;
                }
            }
        }
    }
}

// ---------------- scan pass A: per-chunk local finals ----------------
// grid 512 x 256 threads: wave -> one (b,h,chunk); lane -> d
__global__ void scan_finals(const u16* __restrict__ qkv, const float* __restrict__ decay_param,
                            float* __restrict__ ckv, float* __restrict__ cks) {
    int g    = blockIdx.x * 4 + (threadIdx.x >> 6);   // ((b*NH+h)*NCH + c)
    int lane = threadIdx.x & 63;
    int c = g & (NCH - 1);
    int h = (g >> 5) & (NH - 1);
    int b = g >> 9;
    float decay = sigmoidf(decay_param[h]);
    const u16* kp = qkv + (size_t)(b * TT + c * CLEN) * (3 * HID) + HID + h * HD + lane;
    float skv = 0.f, sks = 0.f;
    for (int t = 0; t < CLEN; ++t) {
        float k = phi(bf2f(kp[0]));
        float v = bf2f(kp[HID]);
        skv = decay * skv + k * v;
        sks = decay * sks + k;
        kp += 3 * HID;
    }
    ckv[(size_t)g * 64 + lane] = skv;
    cks[(size_t)g * 64 + lane] = sks;
}

// ---------------- scan pass B: cross-chunk exclusive prefix (in place) ----------------
// grid 64 x 64: block -> (b,h); lane -> d
__global__ void scan_prefix(float* __restrict__ ckv, float* __restrict__ cks,
                            const float* __restrict__ decay_param) {
    int bh = blockIdx.x;
    int h  = bh & (NH - 1);
    int lane = threadIdx.x;
    float decay = sigmoidf(decay_param[h]);
    float dC = powf(decay, (float)CLEN);
    float* pkv = ckv + (size_t)bh * NCH * 64 + lane;
    float* pks = cks + (size_t)bh * NCH * 64 + lane;
    float fkv = 0.f, fks = 0.f;
    for (int c = 0; c < NCH; ++c) {
        float lkv = pkv[c * 64], lks = pks[c * 64];
        pkv[c * 64] = fkv; pks[c * 64] = fks;
        fkv = fkv * dC + lkv;
        fks = fks * dC + lks;
    }
}

// ---------------- scan pass C: apply with correct init, den-reduce, write attn ----------------
__global__ void scan_apply(const u16* __restrict__ qkv, const float* __restrict__ decay_param,
                           const float* __restrict__ ckv, const float* __restrict__ cks,
                           u16* __restrict__ attn) {
    int g    = blockIdx.x * 4 + (threadIdx.x >> 6);
    int lane = threadIdx.x & 63;
    int c = g & (NCH - 1);
    int h = (g >> 5) & (NH - 1);
    int b = g >> 9;
    float decay = sigmoidf(decay_param[h]);
    float skv = ckv[(size_t)g * 64 + lane];
    float sks = cks[(size_t)g * 64 + lane];
    const u16* qp = qkv + (size_t)(b * TT + c * CLEN) * (3 * HID) + h * HD + lane;
    u16* op = attn + (size_t)(b * TT + c * CLEN) * HID + h * HD + lane;
    for (int t = 0; t < CLEN; ++t) {
        float q = phi(bf2f(qp[0]));
        float k = phi(bf2f(qp[HID]));
        float v = bf2f(qp[2 * HID]);
        skv = decay * skv + k * v;
        sks = decay * sks + k;
        float s = q * sks;
        s += __shfl_xor(s, 32);
        s += __shfl_xor(s, 16);
        s += __shfl_xor(s, 8);
        s += __shfl_xor(s, 4);
        s += __shfl_xor(s, 2);
        s += __shfl_xor(s, 1);
        float den = fmaxf(s, 1e-6f);
        op[0] = f2bf(q * skv / den);
        qp += 3 * HID;
        op += HID;
    }
}

extern "C" void kernel_launch(void* const* d_in, const int* in_sizes, int n_in,
                              void* d_out, int out_size, void* d_ws, size_t ws_size,
                              hipStream_t stream) {
    const float* x     = (const float*)d_in[0];   // [4,4096,1024]
    const float* Wqkv  = (const float*)d_in[1];   // [3072,1024]
    const float* Wout  = (const float*)d_in[2];   // [1024,1024]
    const float* Wgate = (const float*)d_in[3];   // [1024,1024]
    const float* bgate = (const float*)d_in[4];   // [1024]
    const float* decay = (const float*)d_in[5];   // [16]

    // workspace layout (bf16 elements)
    u16* xb     = (u16*)d_ws;                                 // 16384*1024  (aliased as attn later)
    u16* wqkvb  = xb    + (size_t)BT * HID;                   // 3072*1024
    u16* wgateb = wqkvb + (size_t)3 * HID * HID;              // 1024*1024
    u16* woutb  = wgateb + (size_t)HID * HID;                 // 1024*1024
    u16* qkvb   = woutb + (size_t)HID * HID;                  // 16384*3072
    u16* out2b  = qkvb  + (size_t)BT * 3 * HID;               // 16384*1024
    float* ckv  = (float*)(out2b + (size_t)BT * HID);         // 4*16*32*64
    float* cks  = ckv + (size_t)BB * NH * NCH * HD;
    u16* attnb  = xb;  // alias: x dead after GEMM1

    // converts
    {
        int n4 = BT * HID / 4;
        f32_to_bf16_v4<<<n4 / 256, 256, 0, stream>>>((const float4*)x, xb, n4);
        n4 = 3 * HID * HID / 4;
        f32_to_bf16_v4<<<n4 / 256, 256, 0, stream>>>((const float4*)Wqkv, wqkvb, n4);
        n4 = HID * HID / 4;
        f32_to_bf16_v4<<<n4 / 256, 256, 0, stream>>>((const float4*)Wgate, wgateb, n4);
        f32_to_bf16_v4<<<n4 / 256, 256, 0, stream>>>((const float4*)Wout, woutb, n4);
    }

    // GEMM1: qkv = x @ Wqkv^T  -> bf16 [16384,3072]
    gemm_bt<0><<<dim3(3 * HID / 128, BT / 128), 256, 0, stream>>>(
        xb, wqkvb, BT, 3 * HID, HID, qkvb, nullptr, nullptr, nullptr);

    // decay scans -> attn bf16 [16384,1024]
    scan_finals<<<BB * NH * NCH / 4, 256, 0, stream>>>(qkvb, decay, ckv, cks);
    scan_prefix<<<BB * NH, 64, 0, stream>>>(ckv, cks, decay);
    scan_apply<<<BB * NH * NCH / 4, 256, 0, stream>>>(qkvb, decay, ckv, cks, attnb);

    // GEMM2: gate + blend -> out2 bf16 [16384,1024]
    gemm_bt<1><<<dim3(HID / 128, BT / 128), 256, 0, stream>>>(
        attnb, wgateb, BT, HID, HID, out2b, bgate, attnb, qkvb);

    // GEMM3: final projection -> fp32 d_out
    gemm_bt<2><<<dim3(HID / 128, BT / 128), 256, 0, stream>>>(
        out2b, woutb, BT, HID, HID, d_out, nullptr, nullptr, nullptr);
}

// Round 2
// 413.794 us; speedup vs baseline: 1.1857x; 1.1857x over previous
//
#include <hip/hip_runtime.h>

typedef unsigned short u16;
typedef __bf16 bf16x8 __attribute__((ext_vector_type(8)));
typedef float f32x4 __attribute__((ext_vector_type(4)));

#define BB 4
#define TT 4096
#define HID 1024
#define NH 16
#define HD 64
#define BT (BB*TT)          // 16384 rows
#define NCH 128             // chunks over T
#define LOG_NCH 7
#define CLEN (TT/NCH)       // 32

__device__ __forceinline__ float bf2f(u16 u) {
    return __uint_as_float(((unsigned)u) << 16);
}
__device__ __forceinline__ u16 f2bf(float f) {
    unsigned u = __float_as_uint(f);
    unsigned r = 0x7FFFu + ((u >> 16) & 1u);
    return (u16)((u + r) >> 16);
}
__device__ __forceinline__ float phi(float x) {      // elu(x)+1
    return x > 0.f ? x + 1.f : __expf(x);
}
__device__ __forceinline__ float sigmoidf(float x) {
    return 1.f / (1.f + __expf(-x));
}

// ---------------- fp32 -> bf16 convert (vectorized x4) ----------------
__global__ void f32_to_bf16_v4(const float4* __restrict__ in, u16* __restrict__ out, int n4) {
    int i = blockIdx.x * 256 + threadIdx.x;
    if (i >= n4) return;
    float4 f = in[i];
    ushort4 u;
    u.x = f2bf(f.x); u.y = f2bf(f.y); u.z = f2bf(f.z); u.w = f2bf(f.w);
    ((ushort4*)out)[i] = u;
}

// ---------------- MFMA GEMM: C[M,N] = A[M,K] @ W[N,K]^T (both K-major bf16) ---------
// 128x128 tile, BK=64, 4 waves (each 64x64 via 4x4 of 16x16x32 mfma).
// LDS XOR swizzle: physical 16B-chunk = logical chunk ^ (row&7). Staging permutes
// the per-lane GLOBAL address (same cache lines -> coalescing unchanged); reads
// then hit all 32 banks uniformly (8 accesses/bank for b128 = conflict-free min).
// EPI 0: store bf16 (qkv).  EPI 1: gate epilogue.  EPI 2: store fp32 (final).
template<int EPI>
__global__ __launch_bounds__(256)
void gemm_bt(const u16* __restrict__ A, const u16* __restrict__ Bm,
             int M, int N, int K, void* __restrict__ Cout,
             const float* __restrict__ bg,          // EPI1: bias
             const u16* __restrict__ attn,          // EPI1: attn (bf16, [BT,HID])
             const u16* __restrict__ qkv)           // EPI1: qkv (bf16, [BT,3*HID]) for v
{
    __shared__ u16 As[128 * 64];
    __shared__ u16 Bs[128 * 64];
    const int tid  = threadIdx.x;
    const int wave = tid >> 6;
    const int lane = tid & 63;
    const int m0 = blockIdx.y * 128;
    const int n0 = blockIdx.x * 128;
    const int mw = (wave & 1) * 64;
    const int nw = (wave >> 1) * 64;
    const int r16 = lane & 15;

    f32x4 acc[4][4];
    #pragma unroll
    for (int i = 0; i < 4; ++i)
        #pragma unroll
        for (int j = 0; j < 4; ++j)
            acc[i][j] = (f32x4){0.f, 0.f, 0.f, 0.f};

    for (int k0 = 0; k0 < K; k0 += 64) {
        #pragma unroll
        for (int i = 0; i < 4; ++i) {
            int s   = i * 4 + wave;          // segment 0..15 (wave-uniform)
            int idx = s * 64 + lane;         // 0..1023 linear 16B-chunk index
            int pr  = idx >> 3;              // physical row 0..127
            int pc  = idx & 7;               // physical chunk within row
            int lc  = pc ^ (pr & 7);         // logical chunk to fetch (XOR swizzle)
            const u16* gA = A  + (size_t)(m0 + pr) * K + k0 + lc * 8;
            const u16* gB = Bm + (size_t)(n0 + pr) * K + k0 + lc * 8;
            __builtin_amdgcn_global_load_lds(
                (const __attribute__((address_space(1))) void*)gA,
                (__attribute__((address_space(3))) void*)&As[s * 512], 16, 0, 0);
            __builtin_amdgcn_global_load_lds(
                (const __attribute__((address_space(1))) void*)gB,
                (__attribute__((address_space(3))) void*)&Bs[s * 512], 16, 0, 0);
        }
        __syncthreads();   // drains vmcnt(0) -> LDS writes visible
        #pragma unroll
        for (int s2 = 0; s2 < 2; ++s2) {
            const int lcq = s2 * 4 + (lane >> 4);     // logical chunk of this quarter-wave
            const int pcq = lcq ^ (r16 & 7);          // physical chunk after swizzle
            bf16x8 af[4], bq[4];
            #pragma unroll
            for (int i = 0; i < 4; ++i)
                af[i] = *(const bf16x8*)&As[(mw + i * 16 + r16) * 64 + pcq * 8];
            #pragma unroll
            for (int j = 0; j < 4; ++j)
                bq[j] = *(const bf16x8*)&Bs[(nw + j * 16 + r16) * 64 + pcq * 8];
            #pragma unroll
            for (int i = 0; i < 4; ++i)
                #pragma unroll
                for (int j = 0; j < 4; ++j)
                    acc[i][j] = __builtin_amdgcn_mfma_f32_16x16x32_bf16(af[i], bq[j], acc[i][j], 0, 0, 0);
        }
        __syncthreads();   // all reads done before next stage overwrites
    }

    // epilogue: C/D layout col=lane&15, row=(lane>>4)*4+reg  [m89/m91 verified]
    #pragma unroll
    for (int i = 0; i < 4; ++i) {
        int rowb = m0 + mw + i * 16 + (lane >> 4) * 4;
        #pragma unroll
        for (int j = 0; j < 4; ++j) {
            int col = n0 + nw + j * 16 + r16;
            #pragma unroll
            for (int r = 0; r < 4; ++r) {
                float v = acc[i][j][r];
                size_t row = (size_t)(rowb + r);
                if (EPI == 0) {
                    ((u16*)Cout)[row * N + col] = f2bf(v);
                } else if (EPI == 1) {
                    float g  = sigmoidf(v + bg[col]);
                    float at = bf2f(attn[row * HID + col]);
                    float vd = bf2f(qkv[row * (3 * HID) + 2 * HID + col]);
                    ((u16*)Cout)[row * HID + col] = f2bf(g * at + (1.f - g) * vd);
                } else {
                    ((float*)Cout)[row * N + col] = v;
                }
            }
        }
    }
}

// ---------------- scan pass A: per-chunk local finals ----------------
// wave -> one (b,h,chunk); lane -> d
__global__ void scan_finals(const u16* __restrict__ qkv, const float* __restrict__ decay_param,
                            float* __restrict__ ckv, float* __restrict__ cks) {
    int g    = blockIdx.x * 4 + (threadIdx.x >> 6);   // ((b*NH+h)*NCH + c)
    int lane = threadIdx.x & 63;
    int c = g & (NCH - 1);
    int h = (g >> LOG_NCH) & (NH - 1);
    int b = g >> (LOG_NCH + 4);
    float decay = sigmoidf(decay_param[h]);
    const u16* kp = qkv + (size_t)(b * TT + c * CLEN) * (3 * HID) + HID + h * HD + lane;
    float skv = 0.f, sks = 0.f;
    for (int t = 0; t < CLEN; ++t) {
        float k = phi(bf2f(kp[0]));
        float v = bf2f(kp[HID]);
        skv = decay * skv + k * v;
        sks = decay * sks + k;
        kp += 3 * HID;
    }
    ckv[(size_t)g * 64 + lane] = skv;
    cks[(size_t)g * 64 + lane] = sks;
}

// ---------------- scan pass B: cross-chunk exclusive prefix (in place) ----------------
// block -> (b,h); lane -> d
__global__ void scan_prefix(float* __restrict__ ckv, float* __restrict__ cks,
                            const float* __restrict__ decay_param) {
    int bh = blockIdx.x;
    int h  = bh & (NH - 1);
    int lane = threadIdx.x;
    float decay = sigmoidf(decay_param[h]);
    float dC = powf(decay, (float)CLEN);
    float* pkv = ckv + (size_t)bh * NCH * 64 + lane;
    float* pks = cks + (size_t)bh * NCH * 64 + lane;
    float fkv = 0.f, fks = 0.f;
    for (int c = 0; c < NCH; ++c) {
        float lkv = pkv[c * 64], lks = pks[c * 64];
        pkv[c * 64] = fkv; pks[c * 64] = fks;
        fkv = fkv * dC + lkv;
        fks = fks * dC + lks;
    }
}

// ---------------- scan pass C: apply with correct init, den-reduce, write attn ----------------
__global__ void scan_apply(const u16* __restrict__ qkv, const float* __restrict__ decay_param,
                           const float* __restrict__ ckv, const float* __restrict__ cks,
                           u16* __restrict__ attn) {
    int g    = blockIdx.x * 4 + (threadIdx.x >> 6);
    int lane = threadIdx.x & 63;
    int c = g & (NCH - 1);
    int h = (g >> LOG_NCH) & (NH - 1);
    int b = g >> (LOG_NCH + 4);
    float decay = sigmoidf(decay_param[h]);
    float skv = ckv[(size_t)g * 64 + lane];
    float sks = cks[(size_t)g * 64 + lane];
    const u16* qp = qkv + (size_t)(b * TT + c * CLEN) * (3 * HID) + h * HD + lane;
    u16* op = attn + (size_t)(b * TT + c * CLEN) * HID + h * HD + lane;
    for (int t = 0; t < CLEN; ++t) {
        float q = phi(bf2f(qp[0]));
        float k = phi(bf2f(qp[HID]));
        float v = bf2f(qp[2 * HID]);
        skv = decay * skv + k * v;
        sks = decay * sks + k;
        float s = q * sks;
        s += __shfl_xor(s, 32);
        s += __shfl_xor(s, 16);
        s += __shfl_xor(s, 8);
        s += __shfl_xor(s, 4);
        s += __shfl_xor(s, 2);
        s += __shfl_xor(s, 1);
        float den = fmaxf(s, 1e-6f);
        op[0] = f2bf(q * skv / den);
        qp += 3 * HID;
        op += HID;
    }
}

extern "C" void kernel_launch(void* const* d_in, const int* in_sizes, int n_in,
                              void* d_out, int out_size, void* d_ws, size_t ws_size,
                              hipStream_t stream) {
    const float* x     = (const float*)d_in[0];   // [4,4096,1024]
    const float* Wqkv  = (const float*)d_in[1];   // [3072,1024]
    const float* Wout  = (const float*)d_in[2];   // [1024,1024]
    const float* Wgate = (const float*)d_in[3];   // [1024,1024]
    const float* bgate = (const float*)d_in[4];   // [1024]
    const float* decay = (const float*)d_in[5];   // [16]

    // workspace layout (bf16 elements)
    u16* xb     = (u16*)d_ws;                                 // 16384*1024  (aliased as attn later)
    u16* wqkvb  = xb    + (size_t)BT * HID;                   // 3072*1024
    u16* wgateb = wqkvb + (size_t)3 * HID * HID;              // 1024*1024
    u16* woutb  = wgateb + (size_t)HID * HID;                 // 1024*1024
    u16* qkvb   = woutb + (size_t)HID * HID;                  // 16384*3072
    u16* out2b  = qkvb  + (size_t)BT * 3 * HID;               // 16384*1024
    float* ckv  = (float*)(out2b + (size_t)BT * HID);         // 4*16*128*64
    float* cks  = ckv + (size_t)BB * NH * NCH * HD;
    u16* attnb  = xb;  // alias: x dead after GEMM1

    // converts
    {
        int n4 = BT * HID / 4;
        f32_to_bf16_v4<<<n4 / 256, 256, 0, stream>>>((const float4*)x, xb, n4);
        n4 = 3 * HID * HID / 4;
        f32_to_bf16_v4<<<n4 / 256, 256, 0, stream>>>((const float4*)Wqkv, wqkvb, n4);
        n4 = HID * HID / 4;
        f32_to_bf16_v4<<<n4 / 256, 256, 0, stream>>>((const float4*)Wgate, wgateb, n4);
        f32_to_bf16_v4<<<n4 / 256, 256, 0, stream>>>((const float4*)Wout, woutb, n4);
    }

    // GEMM1: qkv = x @ Wqkv^T  -> bf16 [16384,3072]
    gemm_bt<0><<<dim3(3 * HID / 128, BT / 128), 256, 0, stream>>>(
        xb, wqkvb, BT, 3 * HID, HID, qkvb, nullptr, nullptr, nullptr);

    // decay scans -> attn bf16 [16384,1024]
    scan_finals<<<BB * NH * NCH / 4, 256, 0, stream>>>(qkvb, decay, ckv, cks);
    scan_prefix<<<BB * NH, 64, 0, stream>>>(ckv, cks, decay);
    scan_apply<<<BB * NH * NCH / 4, 256, 0, stream>>>(qkvb, decay, ckv, cks, attnb);

    // GEMM2: gate + blend -> out2 bf16 [16384,1024]
    gemm_bt<1><<<dim3(HID / 128, BT / 128), 256, 0, stream>>>(
        attnb, wgateb, BT, HID, HID, out2b, bgate, attnb, qkvb);

    // GEMM3: final projection -> fp32 d_out
    gemm_bt<2><<<dim3(HID / 128, BT / 128), 256, 0, stream>>>(
        out2b, woutb, BT, HID, HID, d_out, nullptr, nullptr, nullptr);
}

// Round 3
// 398.549 us; speedup vs baseline: 1.2311x; 1.0383x over previous
//
#include <hip/hip_runtime.h>

typedef unsigned short u16;
typedef __bf16 bf16x8 __attribute__((ext_vector_type(8)));
typedef float f32x4 __attribute__((ext_vector_type(4)));

#define BB 4
#define TT 4096
#define HID 1024
#define NH 16
#define HD 64
#define BT (BB*TT)          // 16384 rows
#define NCH 128             // chunks over T
#define LOG_NCH 7
#define CLEN (TT/NCH)       // 32

__device__ __forceinline__ float bf2f(u16 u) {
    return __uint_as_float(((unsigned)u) << 16);
}
__device__ __forceinline__ u16 f2bf(float f) {
    unsigned u = __float_as_uint(f);
    unsigned r = 0x7FFFu + ((u >> 16) & 1u);
    return (u16)((u + r) >> 16);
}
__device__ __forceinline__ float phi(float x) {      // elu(x)+1
    return x > 0.f ? x + 1.f : __expf(x);
}
__device__ __forceinline__ float sigmoidf(float x) {
    return 1.f / (1.f + __expf(-x));
}
__device__ __forceinline__ float4 u4_to_f4(ushort4 u) {
    return make_float4(bf2f(u.x), bf2f(u.y), bf2f(u.z), bf2f(u.w));
}

// ---------------- fused fp32 -> bf16 convert (one launch for all 4 tensors) ----------
#define CN1 (BT*HID/4)          // x      : 4194304
#define CN2 (3*HID*HID/4)       // Wqkv   :  786432
#define CN3 (HID*HID/4)         // Wgate  :  262144
#define CN4 (HID*HID/4)         // Wout   :  262144
__global__ void convert_all(const float4* __restrict__ x,    const float4* __restrict__ wqkv,
                            const float4* __restrict__ wgate, const float4* __restrict__ wout,
                            ushort4* __restrict__ xb,    ushort4* __restrict__ wqkvb,
                            ushort4* __restrict__ wgateb, ushort4* __restrict__ woutb) {
    int i = blockIdx.x * 256 + threadIdx.x;
    const float4* src; ushort4* dst; int j;
    if (i < CN1)                 { src = x;     dst = xb;     j = i; }
    else if (i < CN1+CN2)        { src = wqkv;  dst = wqkvb;  j = i - CN1; }
    else if (i < CN1+CN2+CN3)    { src = wgate; dst = wgateb; j = i - CN1 - CN2; }
    else                         { src = wout;  dst = woutb;  j = i - CN1 - CN2 - CN3; }
    float4 f = src[j];
    ushort4 u;
    u.x = f2bf(f.x); u.y = f2bf(f.y); u.z = f2bf(f.z); u.w = f2bf(f.w);
    dst[j] = u;
}

// ---------------- MFMA GEMM: C[M,N] = A[M,K] @ W[N,K]^T (both K-major bf16) ---------
// 128x128 tile, BK=64, 4 waves (each 64x64 via 4x4 of 16x16x32 mfma).
// LDS XOR swizzle: physical 16B-chunk = logical chunk ^ (row&7). Verified round 2:
// SQ_LDS_BANK_CONFLICT = 0. EPI 0: store bf16. EPI 1: gate epilogue. EPI 2: fp32.
template<int EPI>
__global__ __launch_bounds__(256)
void gemm_bt(const u16* __restrict__ A, const u16* __restrict__ Bm,
             int M, int N, int K, void* __restrict__ Cout,
             const float* __restrict__ bg,
             const u16* __restrict__ attn,
             const u16* __restrict__ qkv)
{
    __shared__ u16 As[128 * 64];
    __shared__ u16 Bs[128 * 64];
    const int tid  = threadIdx.x;
    const int wave = tid >> 6;
    const int lane = tid & 63;
    const int m0 = blockIdx.y * 128;
    const int n0 = blockIdx.x * 128;
    const int mw = (wave & 1) * 64;
    const int nw = (wave >> 1) * 64;
    const int r16 = lane & 15;

    f32x4 acc[4][4];
    #pragma unroll
    for (int i = 0; i < 4; ++i)
        #pragma unroll
        for (int j = 0; j < 4; ++j)
            acc[i][j] = (f32x4){0.f, 0.f, 0.f, 0.f};

    for (int k0 = 0; k0 < K; k0 += 64) {
        #pragma unroll
        for (int i = 0; i < 4; ++i) {
            int s   = i * 4 + wave;          // segment 0..15 (wave-uniform)
            int idx = s * 64 + lane;         // linear 16B-chunk index
            int pr  = idx >> 3;
            int pc  = idx & 7;
            int lc  = pc ^ (pr & 7);         // XOR swizzle
            const u16* gA = A  + (size_t)(m0 + pr) * K + k0 + lc * 8;
            const u16* gB = Bm + (size_t)(n0 + pr) * K + k0 + lc * 8;
            __builtin_amdgcn_global_load_lds(
                (const __attribute__((address_space(1))) void*)gA,
                (__attribute__((address_space(3))) void*)&As[s * 512], 16, 0, 0);
            __builtin_amdgcn_global_load_lds(
                (const __attribute__((address_space(1))) void*)gB,
                (__attribute__((address_space(3))) void*)&Bs[s * 512], 16, 0, 0);
        }
        __syncthreads();
        #pragma unroll
        for (int s2 = 0; s2 < 2; ++s2) {
            const int lcq = s2 * 4 + (lane >> 4);
            const int pcq = lcq ^ (r16 & 7);
            bf16x8 af[4], bq[4];
            #pragma unroll
            for (int i = 0; i < 4; ++i)
                af[i] = *(const bf16x8*)&As[(mw + i * 16 + r16) * 64 + pcq * 8];
            #pragma unroll
            for (int j = 0; j < 4; ++j)
                bq[j] = *(const bf16x8*)&Bs[(nw + j * 16 + r16) * 64 + pcq * 8];
            #pragma unroll
            for (int i = 0; i < 4; ++i)
                #pragma unroll
                for (int j = 0; j < 4; ++j)
                    acc[i][j] = __builtin_amdgcn_mfma_f32_16x16x32_bf16(af[i], bq[j], acc[i][j], 0, 0, 0);
        }
        __syncthreads();
    }

    // epilogue: C/D layout col=lane&15, row=(lane>>4)*4+reg
    #pragma unroll
    for (int i = 0; i < 4; ++i) {
        int rowb = m0 + mw + i * 16 + (lane >> 4) * 4;
        #pragma unroll
        for (int j = 0; j < 4; ++j) {
            int col = n0 + nw + j * 16 + r16;
            #pragma unroll
            for (int r = 0; r < 4; ++r) {
                float v = acc[i][j][r];
                size_t row = (size_t)(rowb + r);
                if (EPI == 0) {
                    ((u16*)Cout)[row * N + col] = f2bf(v);
                } else if (EPI == 1) {
                    float g  = sigmoidf(v + bg[col]);
                    float at = bf2f(attn[row * HID + col]);
                    float vd = bf2f(qkv[row * (3 * HID) + 2 * HID + col]);
                    ((u16*)Cout)[row * HID + col] = f2bf(g * at + (1.f - g) * vd);
                } else {
                    ((float*)Cout)[row * N + col] = v;
                }
            }
        }
    }
}

// ---------------- small-tile MFMA GEMM: 64x128 tile, for low-N GEMMs ---------------
// 2048 blocks for M=16384,N=1024 -> 8 blocks/CU of work (vs 4 with 128-tile), 24 KB
// LDS -> 6 blocks/CU residency. Wave w: rows (w&1)*32..+32, cols (w>>1)*64..+64.
template<int EPI>
__global__ __launch_bounds__(256)
void gemm_bt_sm(const u16* __restrict__ A, const u16* __restrict__ Bm,
                int M, int N, int K, void* __restrict__ Cout,
                const float* __restrict__ bg,
                const u16* __restrict__ attn,
                const u16* __restrict__ qkv)
{
    __shared__ u16 As[64 * 64];
    __shared__ u16 Bs[128 * 64];
    const int tid  = threadIdx.x;
    const int wave = tid >> 6;
    const int lane = tid & 63;
    const int m0 = blockIdx.y * 64;
    const int n0 = blockIdx.x * 128;
    const int mw = (wave & 1) * 32;
    const int nw = (wave >> 1) * 64;
    const int r16 = lane & 15;

    f32x4 acc[2][4];
    #pragma unroll
    for (int i = 0; i < 2; ++i)
        #pragma unroll
        for (int j = 0; j < 4; ++j)
            acc[i][j] = (f32x4){0.f, 0.f, 0.f, 0.f};

    for (int k0 = 0; k0 < K; k0 += 64) {
        #pragma unroll
        for (int i = 0; i < 4; ++i) {
            int s   = i * 4 + wave;          // B segment 0..15
            int idx = s * 64 + lane;
            int pr  = idx >> 3;
            int pc  = idx & 7;
            int lc  = pc ^ (pr & 7);
            const u16* gB = Bm + (size_t)(n0 + pr) * K + k0 + lc * 8;
            __builtin_amdgcn_global_load_lds(
                (const __attribute__((address_space(1))) void*)gB,
                (__attribute__((address_space(3))) void*)&Bs[s * 512], 16, 0, 0);
            if (i < 2) {                     // A segments 0..7 (64 rows)
                const u16* gA = A + (size_t)(m0 + pr) * K + k0 + lc * 8;
                __builtin_amdgcn_global_load_lds(
                    (const __attribute__((address_space(1))) void*)gA,
                    (__attribute__((address_space(3))) void*)&As[s * 512], 16, 0, 0);
            }
        }
        __syncthreads();
        #pragma unroll
        for (int s2 = 0; s2 < 2; ++s2) {
            const int lcq = s2 * 4 + (lane >> 4);
            const int pcq = lcq ^ (r16 & 7);
            bf16x8 af[2], bq[4];
            #pragma unroll
            for (int i = 0; i < 2; ++i)
                af[i] = *(const bf16x8*)&As[(mw + i * 16 + r16) * 64 + pcq * 8];
            #pragma unroll
            for (int j = 0; j < 4; ++j)
                bq[j] = *(const bf16x8*)&Bs[(nw + j * 16 + r16) * 64 + pcq * 8];
            #pragma unroll
            for (int i = 0; i < 2; ++i)
                #pragma unroll
                for (int j = 0; j < 4; ++j)
                    acc[i][j] = __builtin_amdgcn_mfma_f32_16x16x32_bf16(af[i], bq[j], acc[i][j], 0, 0, 0);
        }
        __syncthreads();
    }

    #pragma unroll
    for (int i = 0; i < 2; ++i) {
        int rowb = m0 + mw + i * 16 + (lane >> 4) * 4;
        #pragma unroll
        for (int j = 0; j < 4; ++j) {
            int col = n0 + nw + j * 16 + r16;
            #pragma unroll
            for (int r = 0; r < 4; ++r) {
                float v = acc[i][j][r];
                size_t row = (size_t)(rowb + r);
                if (EPI == 1) {
                    float g  = sigmoidf(v + bg[col]);
                    float at = bf2f(attn[row * HID + col]);
                    float vd = bf2f(qkv[row * (3 * HID) + 2 * HID + col]);
                    ((u16*)Cout)[row * HID + col] = f2bf(g * at + (1.f - g) * vd);
                } else {
                    ((float*)Cout)[row * N + col] = v;
                }
            }
        }
    }
}

// ---------------- scan pass A: per-chunk local finals (vectorized x4) --------------
// 16-lane group -> one (b,h,chunk); sub-lane sl handles d = sl*4..sl*4+3
__global__ void scan_finals(const u16* __restrict__ qkv, const float* __restrict__ decay_param,
                            float* __restrict__ ckv, float* __restrict__ cks) {
    int g  = blockIdx.x * 16 + (threadIdx.x >> 4);    // ((b*NH+h)*NCH + c)
    int sl = threadIdx.x & 15;
    int c = g & (NCH - 1);
    int h = (g >> LOG_NCH) & (NH - 1);
    int b = g >> (LOG_NCH + 4);
    float decay = sigmoidf(decay_param[h]);
    const u16* kp = qkv + (size_t)(b * TT + c * CLEN) * (3 * HID) + HID + h * HD + sl * 4;
    float4 skv = make_float4(0.f, 0.f, 0.f, 0.f);
    float4 sks = make_float4(0.f, 0.f, 0.f, 0.f);
    for (int t = 0; t < CLEN; ++t) {
        float4 k = u4_to_f4(*(const ushort4*)kp);
        float4 v = u4_to_f4(*(const ushort4*)(kp + HID));
        k.x = phi(k.x); k.y = phi(k.y); k.z = phi(k.z); k.w = phi(k.w);
        skv.x = decay * skv.x + k.x * v.x;  skv.y = decay * skv.y + k.y * v.y;
        skv.z = decay * skv.z + k.z * v.z;  skv.w = decay * skv.w + k.w * v.w;
        sks.x = decay * sks.x + k.x;        sks.y = decay * sks.y + k.y;
        sks.z = decay * sks.z + k.z;        sks.w = decay * sks.w + k.w;
        kp += 3 * HID;
    }
    *(float4*)(ckv + (size_t)g * 64 + sl * 4) = skv;
    *(float4*)(cks + (size_t)g * 64 + sl * 4) = sks;
}

// ---------------- scan pass B: cross-chunk exclusive prefix (in place) -------------
__global__ void scan_prefix(float* __restrict__ ckv, float* __restrict__ cks,
                            const float* __restrict__ decay_param) {
    int bh = blockIdx.x;
    int h  = bh & (NH - 1);
    int lane = threadIdx.x;
    float decay = sigmoidf(decay_param[h]);
    float dC = powf(decay, (float)CLEN);
    float* pkv = ckv + (size_t)bh * NCH * 64 + lane;
    float* pks = cks + (size_t)bh * NCH * 64 + lane;
    float fkv = 0.f, fks = 0.f;
    for (int c = 0; c < NCH; ++c) {
        float lkv = pkv[c * 64], lks = pks[c * 64];
        pkv[c * 64] = fkv; pks[c * 64] = fks;
        fkv = fkv * dC + lkv;
        fks = fks * dC + lks;
    }
}

// ---------------- scan pass C: apply with init, den-reduce, write attn (x4) --------
__global__ void scan_apply(const u16* __restrict__ qkv, const float* __restrict__ decay_param,
                           const float* __restrict__ ckv, const float* __restrict__ cks,
                           u16* __restrict__ attn) {
    int g  = blockIdx.x * 16 + (threadIdx.x >> 4);
    int sl = threadIdx.x & 15;
    int c = g & (NCH - 1);
    int h = (g >> LOG_NCH) & (NH - 1);
    int b = g >> (LOG_NCH + 4);
    float decay = sigmoidf(decay_param[h]);
    float4 skv = *(const float4*)(ckv + (size_t)g * 64 + sl * 4);
    float4 sks = *(const float4*)(cks + (size_t)g * 64 + sl * 4);
    const u16* qp = qkv + (size_t)(b * TT + c * CLEN) * (3 * HID) + h * HD + sl * 4;
    u16* op = attn + (size_t)(b * TT + c * CLEN) * HID + h * HD + sl * 4;
    for (int t = 0; t < CLEN; ++t) {
        float4 q = u4_to_f4(*(const ushort4*)qp);
        float4 k = u4_to_f4(*(const ushort4*)(qp + HID));
        float4 v = u4_to_f4(*(const ushort4*)(qp + 2 * HID));
        q.x = phi(q.x); q.y = phi(q.y); q.z = phi(q.z); q.w = phi(q.w);
        k.x = phi(k.x); k.y = phi(k.y); k.z = phi(k.z); k.w = phi(k.w);
        skv.x = decay * skv.x + k.x * v.x;  skv.y = decay * skv.y + k.y * v.y;
        skv.z = decay * skv.z + k.z * v.z;  skv.w = decay * skv.w + k.w * v.w;
        sks.x = decay * sks.x + k.x;        sks.y = decay * sks.y + k.y;
        sks.z = decay * sks.z + k.z;        sks.w = decay * sks.w + k.w;
        float s = q.x * sks.x + q.y * sks.y + q.z * sks.z + q.w * sks.w;
        s += __shfl_xor(s, 8);
        s += __shfl_xor(s, 4);
        s += __shfl_xor(s, 2);
        s += __shfl_xor(s, 1);
        float inv = 1.f / fmaxf(s, 1e-6f);
        ushort4 o;
        o.x = f2bf(q.x * skv.x * inv); o.y = f2bf(q.y * skv.y * inv);
        o.z = f2bf(q.z * skv.z * inv); o.w = f2bf(q.w * skv.w * inv);
        *(ushort4*)op = o;
        qp += 3 * HID;
        op += HID;
    }
}

extern "C" void kernel_launch(void* const* d_in, const int* in_sizes, int n_in,
                              void* d_out, int out_size, void* d_ws, size_t ws_size,
                              hipStream_t stream) {
    const float* x     = (const float*)d_in[0];   // [4,4096,1024]
    const float* Wqkv  = (const float*)d_in[1];   // [3072,1024]
    const float* Wout  = (const float*)d_in[2];   // [1024,1024]
    const float* Wgate = (const float*)d_in[3];   // [1024,1024]
    const float* bgate = (const float*)d_in[4];   // [1024]
    const float* decay = (const float*)d_in[5];   // [16]

    // workspace layout (bf16 elements)
    u16* xb     = (u16*)d_ws;                                 // 16384*1024 (aliased as attn later)
    u16* wqkvb  = xb    + (size_t)BT * HID;                   // 3072*1024
    u16* wgateb = wqkvb + (size_t)3 * HID * HID;              // 1024*1024
    u16* woutb  = wgateb + (size_t)HID * HID;                 // 1024*1024
    u16* qkvb   = woutb + (size_t)HID * HID;                  // 16384*3072
    u16* out2b  = qkvb  + (size_t)BT * 3 * HID;               // 16384*1024
    float* ckv  = (float*)(out2b + (size_t)BT * HID);         // 4*16*128*64
    float* cks  = ckv + (size_t)BB * NH * NCH * HD;
    u16* attnb  = xb;  // alias: x dead after GEMM1

    // fused converts (one launch)
    convert_all<<<(CN1 + CN2 + CN3 + CN4) / 256, 256, 0, stream>>>(
        (const float4*)x, (const float4*)Wqkv, (const float4*)Wgate, (const float4*)Wout,
        (ushort4*)xb, (ushort4*)wqkvb, (ushort4*)wgateb, (ushort4*)woutb);

    // GEMM1: qkv = x @ Wqkv^T  -> bf16 [16384,3072]
    gemm_bt<0><<<dim3(3 * HID / 128, BT / 128), 256, 0, stream>>>(
        xb, wqkvb, BT, 3 * HID, HID, qkvb, nullptr, nullptr, nullptr);

    // decay scans -> attn bf16 [16384,1024]
    scan_finals<<<BB * NH * NCH / 16, 256, 0, stream>>>(qkvb, decay, ckv, cks);
    scan_prefix<<<BB * NH, 64, 0, stream>>>(ckv, cks, decay);
    scan_apply<<<BB * NH * NCH / 16, 256, 0, stream>>>(qkvb, decay, ckv, cks, attnb);

    // GEMM2: gate + blend -> out2 bf16 [16384,1024]  (small tile: 2048 blocks)
    gemm_bt_sm<1><<<dim3(HID / 128, BT / 64), 256, 0, stream>>>(
        attnb, wgateb, BT, HID, HID, out2b, bgate, attnb, qkvb);

    // GEMM3: final projection -> fp32 d_out  (small tile)
    gemm_bt_sm<2><<<dim3(HID / 128, BT / 64), 256, 0, stream>>>(
        out2b, woutb, BT, HID, HID, d_out, nullptr, nullptr, nullptr);
}